// Round 1
// 723.968 us; speedup vs baseline: 1.1973x; 1.1973x over previous
//
#include <hip/hip_runtime.h>

constexpr int kNodes = 1000000;
constexpr int kEdges = 32000000;

// ---------------- Tile-sorted scatter path ----------------
// 256 buckets x 4096 nodes. Record u32 = (node&4095)<<16 | q16,
// q16 = clamp(round((orc_other+1)*32768), 0, 65535)  (error <= 1.5e-5).
// Pad record = 0x10000000 (local node 4096 -> dummy accumulator slot, adds
// nothing to any real node, so bucket_accum needs NO sentinel branch).
// Edges processed in tiles of 4096 (=> 8192 records); per-bucket counts are
// padded to a multiple of 4 records (16 B) so every segment is int4-aligned.
constexpr int NB = 256;
constexpr int BSHIFT = 12;
constexpr int BNODES = 4096;
constexpr int NBUSED = (kNodes + BNODES - 1) / BNODES;   // 245
constexpr int EPT = 4096;                 // edges per tile
constexpr int TILES = (kEdges + EPT - 1) / EPT;          // 7813
constexpr int TSTRIDE = 8960;             // 2*EPT + 256*3 padding, mult of 4
constexpr unsigned PADREC = 0x10000000u;
constexpr int SPLIT = 2;                  // tile-halves per bucket in accum

constexpr size_t kRecBytes  = (size_t)TILES * TSTRIDE * 4;       // ~280 MB
constexpr size_t kTblOff    = kRecBytes;
constexpr size_t kTblBytes  = ((size_t)(NB + 1) * TILES * 2 + 15) & ~(size_t)15;
constexpr size_t kAccOff    = kTblOff + kTblBytes;
constexpr size_t kAccBytes  = (size_t)SPLIT * kNodes * 4;        // 8 MB
constexpr size_t kOrcqOff   = kAccOff + kAccBytes;
constexpr size_t kOrcqBytes = (size_t)kNodes * 2;                // 2 MB
constexpr size_t kWsNeeded  = kOrcqOff + kOrcqBytes;

__global__ __launch_bounds__(256) void quant_orc(
        const float* __restrict__ orc, unsigned short* __restrict__ orcq) {
    const int i = (blockIdx.x * 256 + threadIdx.x) * 4;
    if (i >= kNodes) return;
    const float4 v = *reinterpret_cast<const float4*>(orc + i);
    unsigned q0 = __float2uint_rn((v.x + 1.0f) * 32768.0f);
    unsigned q1 = __float2uint_rn((v.y + 1.0f) * 32768.0f);
    unsigned q2 = __float2uint_rn((v.z + 1.0f) * 32768.0f);
    unsigned q3 = __float2uint_rn((v.w + 1.0f) * 32768.0f);
    q0 = q0 > 65535u ? 65535u : q0;
    q1 = q1 > 65535u ? 65535u : q1;
    q2 = q2 > 65535u ? 65535u : q2;
    q3 = q3 > 65535u ? 65535u : q3;
    ushort4 q;
    q.x = (unsigned short)q0; q.y = (unsigned short)q1;
    q.z = (unsigned short)q2; q.w = (unsigned short)q3;
    *reinterpret_cast<ushort4*>(orcq + i) = q;
}

__global__ __launch_bounds__(1024) void scatter_sort(
        const int* __restrict__ ei, const unsigned short* __restrict__ orcq,
        unsigned* __restrict__ rec, unsigned short* __restrict__ tbl) {
    __shared__ alignas(16) unsigned reorder[TSTRIDE];  // 35 KB
    __shared__ unsigned cnt[NB];                       // hist -> cursor
    __shared__ unsigned totsh;
    const int tid = threadIdx.x;
    const int t = blockIdx.x;
    const int e0 = t * EPT;
    const int ne = min(EPT, kEdges - e0);   // 4096, last tile 2048 (mult of 4)
    const int k4 = tid * 4;

    // init: pad-fill reorder (pad records are harmless in accum), zero hist
    {
        int4 p4; p4.x = p4.y = p4.z = p4.w = (int)PADREC;
        for (int k = k4; k < TSTRIDE; k += 4096)
            *reinterpret_cast<int4*>(reorder + k) = p4;
    }
    if (tid < NB) cnt[tid] = 0u;
    __syncthreads();

    // phase 1: edges -> registers, histogram, and EARLY-ISSUED orcq gathers
    // (gather latency drains under the histogram + scan phases)
    int4 s4, d4;
    s4.x = s4.y = s4.z = s4.w = 0; d4 = s4;
    unsigned pq0 = 0, pq1 = 0, pq2 = 0, pq3 = 0;  // (q_for_d<<16)|q_for_s
    const bool act = k4 < ne;
    if (act) {
        s4 = *reinterpret_cast<const int4*>(ei + e0 + k4);
        d4 = *reinterpret_cast<const int4*>(ei + kEdges + e0 + k4);
        const unsigned a0 = orcq[d4.x], a1 = orcq[d4.y],
                       a2 = orcq[d4.z], a3 = orcq[d4.w];   // q(orc[d]) -> s-rec
        const unsigned b0 = orcq[s4.x], b1 = orcq[s4.y],
                       b2 = orcq[s4.z], b3 = orcq[s4.w];   // q(orc[s]) -> d-rec
        atomicAdd(&cnt[(unsigned)s4.x >> BSHIFT], 1u);
        atomicAdd(&cnt[(unsigned)s4.y >> BSHIFT], 1u);
        atomicAdd(&cnt[(unsigned)s4.z >> BSHIFT], 1u);
        atomicAdd(&cnt[(unsigned)s4.w >> BSHIFT], 1u);
        atomicAdd(&cnt[(unsigned)d4.x >> BSHIFT], 1u);
        atomicAdd(&cnt[(unsigned)d4.y >> BSHIFT], 1u);
        atomicAdd(&cnt[(unsigned)d4.z >> BSHIFT], 1u);
        atomicAdd(&cnt[(unsigned)d4.w >> BSHIFT], 1u);
        pq0 = a0 | (b0 << 16);
        pq1 = a1 | (b1 << 16);
        pq2 = a2 | (b2 << 16);
        pq3 = a3 | (b3 << 16);
    }
    __syncthreads();

    // phase 2: wave-0 shuffle scan of padded counts (2 barriers total)
    if (tid < 64) {
        unsigned c0 = cnt[4 * tid + 0], c1 = cnt[4 * tid + 1];
        unsigned c2 = cnt[4 * tid + 2], c3 = cnt[4 * tid + 3];
        c0 = (c0 + 3u) & ~3u; c1 = (c1 + 3u) & ~3u;
        c2 = (c2 + 3u) & ~3u; c3 = (c3 + 3u) & ~3u;
        const unsigned loc = c0 + c1 + c2 + c3;
        unsigned inc = loc;
        #pragma unroll
        for (int d = 1; d < 64; d <<= 1) {
            const unsigned v = (unsigned)__shfl_up((int)inc, d, 64);
            if (tid >= d) inc += v;
        }
        unsigned base = inc - loc;
        cnt[4 * tid + 0] = base;
        tbl[(size_t)(4 * tid + 0) * TILES + t] = (unsigned short)base;
        base += c0;
        cnt[4 * tid + 1] = base;
        tbl[(size_t)(4 * tid + 1) * TILES + t] = (unsigned short)base;
        base += c1;
        cnt[4 * tid + 2] = base;
        tbl[(size_t)(4 * tid + 2) * TILES + t] = (unsigned short)base;
        base += c2;
        cnt[4 * tid + 3] = base;
        tbl[(size_t)(4 * tid + 3) * TILES + t] = (unsigned short)base;
        if (tid == 63) {
            totsh = inc;
            tbl[(size_t)NB * TILES + t] = (unsigned short)inc;
        }
    }
    __syncthreads();

    // phase 3: rank + scatter records into reorder buffer (from registers)
    if (act) {
        #define RANK1(S, D, PQ) { \
            const unsigned rs_ = atomicAdd(&cnt[(unsigned)(S) >> BSHIFT], 1u); \
            reorder[rs_] = (((unsigned)(S) & (BNODES - 1)) << 16) | ((PQ) & 0xFFFFu); \
            const unsigned rd_ = atomicAdd(&cnt[(unsigned)(D) >> BSHIFT], 1u); \
            reorder[rd_] = (((unsigned)(D) & (BNODES - 1)) << 16) | ((PQ) >> 16); }
        RANK1(s4.x, d4.x, pq0)
        RANK1(s4.y, d4.y, pq1)
        RANK1(s4.z, d4.z, pq2)
        RANK1(s4.w, d4.w, pq3)
        #undef RANK1
    }
    __syncthreads();

    // phase 4: coalesced full-line flush
    const unsigned total = totsh;                 // padded total, mult of 4
    unsigned* __restrict__ g = rec + (size_t)t * TSTRIDE;
    for (unsigned k = (unsigned)k4; k < total; k += 4096)
        *reinterpret_cast<int4*>(g + k) = *reinterpret_cast<const int4*>(reorder + k);
}

__global__ __launch_bounds__(1024) void bucket_accum(
        const unsigned* __restrict__ rec, const unsigned short* __restrict__ tbl,
        unsigned* __restrict__ acc) {
    __shared__ unsigned lacc[BNODES + 4];         // 16.4 KB; slot 4096 = pad sink
    const int tid = threadIdx.x;
    const int b = blockIdx.x >> 1;
    const int half = blockIdx.x & 1;
    for (int k = tid; k < BNODES + 4; k += 1024) lacc[k] = 0u;
    __syncthreads();
    constexpr int TPS = (TILES + SPLIT - 1) / SPLIT;  // 3907
    const int t0 = half * TPS;
    const int t1 = min(TILES, t0 + TPS);
    const unsigned short* __restrict__ r0 = tbl + (size_t)b * TILES;
    const unsigned short* __restrict__ r1 = tbl + (size_t)(b + 1) * TILES;
    for (int t = t0 + tid; t < t1; t += 1024) {
        const unsigned st = r0[t];
        const unsigned en = r1[t];
        const uint4* __restrict__ p =
            reinterpret_cast<const uint4*>(rec + (size_t)t * TSTRIDE + st);
        const unsigned n4 = (en - st) >> 2;
        for (unsigned i = 0; i < n4; ++i) {
            const uint4 v = p[i];
            // deg in bits [24,32), sum(q16) in [0,24). Pad -> lacc[4096].
            atomicAdd(&lacc[v.x >> 16], (v.x & 0xFFFFu) | 0x1000000u);
            atomicAdd(&lacc[v.y >> 16], (v.y & 0xFFFFu) | 0x1000000u);
            atomicAdd(&lacc[v.z >> 16], (v.z & 0xFFFFu) | 0x1000000u);
            atomicAdd(&lacc[v.w >> 16], (v.w & 0xFFFFu) | 0x1000000u);
        }
    }
    __syncthreads();
    const int base = b << BSHIFT;
    unsigned* __restrict__ dst = acc + (size_t)half * kNodes;
    for (int k = tid; k < BNODES; k += 1024) {
        const int n = base + k;
        if (n < kNodes) dst[n] = lacc[k];
    }
}

// ---------------- Fallback (atomic) path ----------------
constexpr float kScale = 1048576.0f;           // 2^20
constexpr float kInvScale = 1.0f / 1048576.0f;
constexpr long long kBias = 1ll << 36;

__global__ __launch_bounds__(256) void zero_acc(unsigned long long* __restrict__ acc) {
    int i = blockIdx.x * 256 + threadIdx.x;
    if (i < kNodes) acc[i] = 0ull;
}

__global__ __launch_bounds__(256) void edge_kernel(
        const int* __restrict__ ei,
        const float* __restrict__ orc,
        unsigned long long* __restrict__ acc) {
    int t = blockIdx.x * 256 + threadIdx.x;
    int e0 = t * 4;
    if (e0 >= kEdges) return;
    const int4 s4 = *reinterpret_cast<const int4*>(ei + e0);
    const int4 d4 = *reinterpret_cast<const int4*>(ei + kEdges + e0);
    const int ss[4] = {s4.x, s4.y, s4.z, s4.w};
    const int dd[4] = {d4.x, d4.y, d4.z, d4.w};
    #pragma unroll
    for (int k = 0; k < 4; ++k) {
        const float os = orc[ss[k]];
        const float od = orc[dd[k]];
        const unsigned long long ps =
            (1ull << 48) + (unsigned long long)(kBias + (long long)__float2ll_rn(od * kScale));
        const unsigned long long pd =
            (1ull << 48) + (unsigned long long)(kBias + (long long)__float2ll_rn(os * kScale));
        atomicAdd(&acc[ss[k]], ps);
        atomicAdd(&acc[dd[k]], pd);
    }
}

// ---------------- Node phase ----------------
// MODE 0: deg<<48 | biased 2^20 fixed sum (u64).
// MODE 3: two u32 partials, each deg<<24 | sum(q16).
template <int MODE>
__global__ __launch_bounds__(256) void node_kernel(
        const float* __restrict__ orc,
        const unsigned long long* __restrict__ acc64,
        const unsigned* __restrict__ acc32,
        const float* __restrict__ W1, const float* __restrict__ b1,
        const float* __restrict__ W2, const float* __restrict__ b2,
        const float* __restrict__ gamma, const float* __restrict__ beta,
        float* __restrict__ out) {
    const int i = blockIdx.x * 256 + threadIdx.x;
    if (i >= kNodes) return;

    const float x0 = orc[i];
    float nb;
    if (MODE == 0) {
        const unsigned long long p = acc64[i];
        const unsigned deg = (unsigned)(p >> 48);
        const long long sf = (long long)(p & ((1ull << 48) - 1)) - (long long)deg * kBias;
        const float s = (float)sf * kInvScale;
        nb = (deg > 0) ? s / (float)deg : 0.0f;
    } else {
        const unsigned p0 = acc32[i];
        const unsigned p1 = acc32[kNodes + i];
        const unsigned deg = (p0 >> 24) + (p1 >> 24);
        const unsigned sumq = (p0 & 0xFFFFFFu) + (p1 & 0xFFFFFFu);
        nb = (deg > 0)
            ? ((float)sumq * (1.0f / 32768.0f) / (float)deg - 1.0f) : 0.0f;
    }

    constexpr float kPi = 3.14159265358979323846f;
    float Phi[16];
    const float n0 = __saturatef((x0 + 1.0f) * 0.5f);
    const float n1 = __saturatef((nb + 1.0f) * 0.5f);
    #pragma unroll
    for (int k = 0; k < 4; ++k) {
        const float a0 = n0 * (float)(k + 1) * kPi;
        const float a1 = n1 * (float)(k + 1) * kPi;
        Phi[2 * k]     = __sinf(a0);
        Phi[2 * k + 1] = __cosf(a0);
        Phi[8 + 2 * k]     = __sinf(a1);
        Phi[8 + 2 * k + 1] = __cosf(a1);
    }

    float y[16];
    #pragma unroll
    for (int d = 0; d < 16; ++d) y[d] = b2[d];
    #pragma unroll
    for (int j = 0; j < 32; ++j) {
        float a = b1[j];
        #pragma unroll
        for (int d = 0; d < 16; ++d) a = fmaf(Phi[d], W1[j * 16 + d], a);
        a = fmaxf(a, 0.0f);
        #pragma unroll
        for (int d = 0; d < 16; ++d) y[d] = fmaf(a, W2[d * 32 + j], y[d]);
    }

    float mu = 0.0f;
    #pragma unroll
    for (int d = 0; d < 16; ++d) mu += y[d];
    mu *= (1.0f / 16.0f);
    float var = 0.0f;
    #pragma unroll
    for (int d = 0; d < 16; ++d) { const float t = y[d] - mu; var = fmaf(t, t, var); }
    var *= (1.0f / 16.0f);
    const float inv = rsqrtf(var + 1e-5f);

    float4* o4 = reinterpret_cast<float4*>(out + (size_t)i * 16);
    #pragma unroll
    for (int q = 0; q < 4; ++q) {
        float4 o;
        o.x = (y[4 * q + 0] - mu) * inv * gamma[4 * q + 0] + beta[4 * q + 0] + Phi[4 * q + 0];
        o.y = (y[4 * q + 1] - mu) * inv * gamma[4 * q + 1] + beta[4 * q + 1] + Phi[4 * q + 1];
        o.z = (y[4 * q + 2] - mu) * inv * gamma[4 * q + 2] + beta[4 * q + 2] + Phi[4 * q + 2];
        o.w = (y[4 * q + 3] - mu) * inv * gamma[4 * q + 3] + beta[4 * q + 3] + Phi[4 * q + 3];
        o4[q] = o;
    }
}

extern "C" void kernel_launch(void* const* d_in, const int* in_sizes, int n_in,
                              void* d_out, int out_size, void* d_ws, size_t ws_size,
                              hipStream_t stream) {
    const float* orc   = (const float*)d_in[0];
    const int*   ei    = (const int*)d_in[1];
    const float* W1    = (const float*)d_in[2];
    const float* b1    = (const float*)d_in[3];
    const float* W2    = (const float*)d_in[4];
    const float* b2    = (const float*)d_in[5];
    const float* gamma = (const float*)d_in[6];
    const float* beta  = (const float*)d_in[7];
    float* out = (float*)d_out;
    char* ws = (char*)d_ws;

    if (ws_size >= kWsNeeded) {
        unsigned* rec = (unsigned*)ws;
        unsigned short* tbl = (unsigned short*)(ws + kTblOff);
        unsigned* acc = (unsigned*)(ws + kAccOff);
        unsigned short* orcq = (unsigned short*)(ws + kOrcqOff);
        quant_orc<<<(kNodes / 4 + 255) / 256, 256, 0, stream>>>(orc, orcq);
        scatter_sort<<<TILES, 1024, 0, stream>>>(ei, orcq, rec, tbl);
        bucket_accum<<<NBUSED * SPLIT, 1024, 0, stream>>>(rec, tbl, acc);
        node_kernel<3><<<(kNodes + 255) / 256, 256, 0, stream>>>(
            orc, nullptr, acc, W1, b1, W2, b2, gamma, beta, out);
    } else {
        unsigned long long* acc = (unsigned long long*)ws;  // 8 MB
        zero_acc<<<(kNodes + 255) / 256, 256, 0, stream>>>(acc);
        edge_kernel<<<(kEdges / 4 + 255) / 256, 256, 0, stream>>>(ei, orc, acc);
        node_kernel<0><<<(kNodes + 255) / 256, 256, 0, stream>>>(
            orc, acc, nullptr, W1, b1, W2, b2, gamma, beta, out);
    }
}